// Round 3
// baseline (537.838 us; speedup 1.0000x reference)
//
#include <hip/hip_runtime.h>

#define N_NODES 25000
#define N_EDGES 400000

// ---------------- fast transcendentals (fp32, ~2ulp) ----------------
__device__ __forceinline__ float fast_sigmoid(float x) {
    return __builtin_amdgcn_rcpf(1.0f + __expf(-x));
}
__device__ __forceinline__ float fast_tanh(float x) {
    return 1.0f - 2.0f * __builtin_amdgcn_rcpf(__expf(2.0f * x) + 1.0f);
}

// XOR swizzle: lane j gets value from lane j^k (stays in 16-lane group, k<16)
#define SWZF(x, k) __int_as_float(__builtin_amdgcn_ds_swizzle(__float_as_int(x), ((k) << 10) | 0x1F))
// Broadcast lane l (0..15) of the 16-lane group to all 16: src=(lane&0x10)|l
#define BC16(x, l) __int_as_float(__builtin_amdgcn_ds_swizzle(__float_as_int(x), ((l) << 5) | 0x10))

// ---------------- K1: hidden0 = nf @ W_init + b_init ; copy; zero cnts --------
__global__ void __launch_bounds__(256) k_init(
        const float* __restrict__ nf, const float* __restrict__ Wini,
        const float* __restrict__ bini,
        float* __restrict__ hidden0, float* __restrict__ hid,
        int* __restrict__ cnt_s, int* __restrict__ cnt_r)
{
    int gtid = blockIdx.x * 256 + threadIdx.x;
    if (gtid <= N_NODES) { cnt_s[gtid] = 0; cnt_r[gtid] = 0; }
    int node = gtid >> 4;
    int j = gtid & 15;
    if (node >= N_NODES) return;

    const float4* nf4 = (const float4*)(nf + node * 32);
    float acc = bini[j];
#pragma unroll
    for (int g = 0; g < 8; ++g) {
        float4 v = nf4[g];
        acc = fmaf(v.x, Wini[(g*4+0)*16 + j], acc);
        acc = fmaf(v.y, Wini[(g*4+1)*16 + j], acc);
        acc = fmaf(v.z, Wini[(g*4+2)*16 + j], acc);
        acc = fmaf(v.w, Wini[(g*4+3)*16 + j], acc);
    }
    hidden0[node*16 + j] = acc;
    hid[node*16 + j] = acc;
}

// ---------------- CSR build (sender CSR + receiver slot assignment) --------
__global__ void __launch_bounds__(256) k_hist(const int* __restrict__ send,
        const int* __restrict__ recv,
        int* __restrict__ cnt_s, int* __restrict__ cnt_r)
{
    int e = blockIdx.x * 256 + threadIdx.x;
    if (e < N_EDGES) {
        atomicAdd(&cnt_s[send[e]], 1);
        atomicAdd(&cnt_r[recv[e]], 1);
    }
}

// grid=2: block 0 scans sender counts, block 1 scans receiver counts
__global__ void __launch_bounds__(1024) k_scan(
        const int* __restrict__ cnt_s, const int* __restrict__ cnt_r,
        int* __restrict__ srow, int* __restrict__ scur,
        int* __restrict__ rrow, int* __restrict__ rcur,
        float* __restrict__ out)
{
    const int* cnt = (blockIdx.x == 0) ? cnt_s : cnt_r;
    int* row = (blockIdx.x == 0) ? srow : rrow;
    int* cur = (blockIdx.x == 0) ? scur : rcur;

    __shared__ int sums[1024];
    int t = threadIdx.x;
    const int CH = (N_NODES + 1023) / 1024 + 1;   // 25 -> covers 25600
    int base = t * CH;
    int s = 0;
    for (int i = 0; i < CH; ++i) {
        int idx = base + i;
        if (idx < N_NODES) s += cnt[idx];
    }
    sums[t] = s;
    __syncthreads();
    for (int off = 1; off < 1024; off <<= 1) {
        int add = (t >= off) ? sums[t - off] : 0;
        __syncthreads();
        sums[t] += add;
        __syncthreads();
    }
    int run = sums[t] - s;
    for (int i = 0; i < CH; ++i) {
        int idx = base + i;
        if (idx < N_NODES) {
            row[idx] = run;
            cur[idx] = run;
            run += cnt[idx];
        }
    }
    if (t == 0) {
        row[N_NODES] = N_EDGES;
        if (blockIdx.x == 0) out[0] = 0.0f;
    }
}

// eids[sp] = e (sender-CSR edge list); dpos[sp] = receiver-sorted slot of e
__global__ void __launch_bounds__(256) k_scatter(const int* __restrict__ send,
        const int* __restrict__ recv,
        int* __restrict__ scur, int* __restrict__ rcur,
        int* __restrict__ eids, int* __restrict__ dpos)
{
    int e = blockIdx.x * 256 + threadIdx.x;
    if (e < N_EDGES) {
        int s = send[e];
        int r = recv[e];
        int sp = atomicAdd(&scur[s], 1);
        int rp = atomicAdd(&rcur[r], 1);
        eids[sp] = e;
        dpos[sp] = rp;
    }
}

// ---------------- K3: per-edge messages, written to receiver-sorted slots ----
// group (16 lanes) = one sender s; lane = message dim m.
// q[f] = sum_h We[f, m*16+h] * h[s,h]  (We is 17KB -> L1-resident)
// per out-edge: emsg[dpos*16+m] = qb + sum_f ef[e,f]*q[f]   (plain 64B store)
__global__ void __launch_bounds__(256) k_msg(
        const float* __restrict__ hid, const float* __restrict__ ef,
        const float* __restrict__ We, const float* __restrict__ be,
        const int* __restrict__ srow, const int* __restrict__ eids,
        const int* __restrict__ dpos, float* __restrict__ emsg)
{
    int gtid = blockIdx.x * 256 + threadIdx.x;
    int s = gtid >> 4;
    int m = gtid & 15;
    if (s >= N_NODES) return;

    float h[16];
    {
        const float4* h4 = (const float4*)(hid + s*16);
        float4 a = h4[0], b = h4[1], c = h4[2], d = h4[3];
        h[0]=a.x;  h[1]=a.y;  h[2]=a.z;  h[3]=a.w;
        h[4]=b.x;  h[5]=b.y;  h[6]=b.z;  h[7]=b.w;
        h[8]=c.x;  h[9]=c.y;  h[10]=c.z; h[11]=c.w;
        h[12]=d.x; h[13]=d.y; h[14]=d.z; h[15]=d.w;
    }
    float q[16];
#pragma unroll
    for (int f = 0; f < 16; ++f) {
        const float4* wf = (const float4*)(We + f*256 + m*16);
        float4 a = wf[0], b = wf[1], c = wf[2], d = wf[3];
        float acc;
        acc  = a.x*h[0]  + a.y*h[1]  + a.z*h[2]  + a.w*h[3];
        acc += b.x*h[4]  + b.y*h[5]  + b.z*h[6]  + b.w*h[7];
        acc += c.x*h[8]  + c.y*h[9]  + c.z*h[10] + c.w*h[11];
        acc += d.x*h[12] + d.y*h[13] + d.z*h[14] + d.w*h[15];
        q[f] = acc;
    }
    float qb;
    {
        const float4* bf = (const float4*)(be + m*16);
        float4 a = bf[0], b = bf[1], c = bf[2], d = bf[3];
        qb  = a.x*h[0]  + a.y*h[1]  + a.z*h[2]  + a.w*h[3];
        qb += b.x*h[4]  + b.y*h[5]  + b.z*h[6]  + b.w*h[7];
        qb += c.x*h[8]  + c.y*h[9]  + c.z*h[10] + c.w*h[11];
        qb += d.x*h[12] + d.y*h[13] + d.z*h[14] + d.w*h[15];
    }

    int beg = srow[s];
    int end = srow[s + 1];
    for (int i = beg; i < end; ++i) {
        int e  = eids[i];
        int dp = dpos[i];
        const float4* e4 = (const float4*)(ef + (size_t)e*16);
        float4 e0 = e4[0], e1 = e4[1], e2 = e4[2], e3 = e4[3];
        float a = qb;
        a = fmaf(e0.x, q[0],  a);
        a = fmaf(e0.y, q[1],  a);
        a = fmaf(e0.z, q[2],  a);
        a = fmaf(e0.w, q[3],  a);
        a = fmaf(e1.x, q[4],  a);
        a = fmaf(e1.y, q[5],  a);
        a = fmaf(e1.z, q[6],  a);
        a = fmaf(e1.w, q[7],  a);
        a = fmaf(e2.x, q[8],  a);
        a = fmaf(e2.y, q[9],  a);
        a = fmaf(e2.z, q[10], a);
        a = fmaf(e2.w, q[11], a);
        a = fmaf(e3.x, q[12], a);
        a = fmaf(e3.y, q[13], a);
        a = fmaf(e3.z, q[14], a);
        a = fmaf(e3.w, q[15], a);
        emsg[(size_t)dp*16 + m] = a;
    }
}

// ---------------- K4: fused segment-sum + GRU (T=32) ----------------
// group = node n, lane j = GRU unit j AND message dim j.
// msum_j = sum of contiguous emsg rows [rrow[n], rrow[n+1]) column j.
// GRU: h broadcast via XOR ds_swizzle; msum enters via lane-broadcast swizzle.
__global__ void __launch_bounds__(256) k_gru(
        const float* __restrict__ hid_in, const float* __restrict__ emsg,
        const int* __restrict__ rrow,
        const float* __restrict__ Wi, const float* __restrict__ Wh,
        const float* __restrict__ bi, const float* __restrict__ bh,
        float* __restrict__ hid_out)
{
    int gtid = blockIdx.x * 256 + threadIdx.x;
    int node = gtid >> 4;
    int j = gtid & 15;
    if (node >= N_NODES) return;

    float Wz[16], Wr[16], Wc[16];
#pragma unroll
    for (int k = 0; k < 16; ++k) {
        int l = j ^ k;
        Wz[k] = Wh[l*48 + j];
        Wr[k] = Wh[l*48 + 16 + j];
        Wc[k] = Wh[l*48 + 32 + j];
    }
    float Wiz = Wi[j], Wir = Wi[16+j], Wih = Wi[32+j];
    float cz   = bi[j] + bh[j];
    float cr   = bi[16+j] + bh[16+j];
    float bih_ = bi[32+j];
    float bhh_ = bh[32+j];

    // segment sum of messages (contiguous rows, 64B coalesced per edge)
    float msum = 0.0f;
    {
        int beg = rrow[node];
        int end = rrow[node + 1];
        for (int i = beg; i < end; ++i)
            msum += emsg[(size_t)i*16 + j];
    }

    float x[16];
    {
        const float4* a4 = (const float4*)(hid_in + node * 16);
#pragma unroll
        for (int g = 0; g < 4; ++g) {
            float4 v = a4[g];
            x[g*4+0]=v.x; x[g*4+1]=v.y; x[g*4+2]=v.z; x[g*4+3]=v.w;
        }
    }

    float hn = 0.0f;

#define STEPK(k) { float v = SWZF(hn, k); \
        az = fmaf(v, Wz[k], az); ar = fmaf(v, Wr[k], ar); ac = fmaf(v, Wc[k], ac); }

#define GRU_STEP(XV) { float xv = (XV); \
        float az = fmaf(xv, Wiz, cz); \
        float ar = fmaf(xv, Wir, cr); \
        float ac = bhh_; \
        az = fmaf(hn, Wz[0], az); \
        ar = fmaf(hn, Wr[0], ar); \
        ac = fmaf(hn, Wc[0], ac); \
        STEPK(1)  STEPK(2)  STEPK(3)  STEPK(4)  STEPK(5) \
        STEPK(6)  STEPK(7)  STEPK(8)  STEPK(9)  STEPK(10) \
        STEPK(11) STEPK(12) STEPK(13) STEPK(14) STEPK(15) \
        float zg  = fast_sigmoid(az); \
        float rg  = fast_sigmoid(ar); \
        float hc = fast_tanh(fmaf(xv, Wih, bih_) + rg * ac); \
        hn = fmaf(zg, hn - hc, hc); }

    GRU_STEP(x[0])  GRU_STEP(x[1])  GRU_STEP(x[2])  GRU_STEP(x[3])
    GRU_STEP(x[4])  GRU_STEP(x[5])  GRU_STEP(x[6])  GRU_STEP(x[7])
    GRU_STEP(x[8])  GRU_STEP(x[9])  GRU_STEP(x[10]) GRU_STEP(x[11])
    GRU_STEP(x[12]) GRU_STEP(x[13]) GRU_STEP(x[14]) GRU_STEP(x[15])

    GRU_STEP(BC16(msum, 0))  GRU_STEP(BC16(msum, 1))
    GRU_STEP(BC16(msum, 2))  GRU_STEP(BC16(msum, 3))
    GRU_STEP(BC16(msum, 4))  GRU_STEP(BC16(msum, 5))
    GRU_STEP(BC16(msum, 6))  GRU_STEP(BC16(msum, 7))
    GRU_STEP(BC16(msum, 8))  GRU_STEP(BC16(msum, 9))
    GRU_STEP(BC16(msum, 10)) GRU_STEP(BC16(msum, 11))
    GRU_STEP(BC16(msum, 12)) GRU_STEP(BC16(msum, 13))
    GRU_STEP(BC16(msum, 14)) GRU_STEP(BC16(msum, 15))

#undef GRU_STEP
#undef STEPK

    hid_out[node*16 + j] = hn;
}

// ---------------- K5: readout ----------------
__global__ void __launch_bounds__(256) k_readout(
        const float* __restrict__ hid, const float* __restrict__ hid0,
        const float* __restrict__ Wri, const float* __restrict__ bri,
        const float* __restrict__ Wrj, const float* __restrict__ brj,
        float* __restrict__ out)
{
    int n = blockIdx.x * 256 + threadIdx.x;
    float val = 0.0f;
    if (n < N_NODES) {
        const float4* h4 = (const float4*)(hid + n * 16);
        const float4* g4 = (const float4*)(hid0 + n * 16);
        float iv = bri[0];
        float jv = brj[0];
#pragma unroll
        for (int g = 0; g < 4; ++g) {
            float4 h  = h4[g];
            float4 h0 = g4[g];
            iv = fmaf(h.x,  Wri[g*4+0], iv);  iv = fmaf(h.y,  Wri[g*4+1], iv);
            iv = fmaf(h.z,  Wri[g*4+2], iv);  iv = fmaf(h.w,  Wri[g*4+3], iv);
            iv = fmaf(h0.x, Wri[16+g*4+0], iv); iv = fmaf(h0.y, Wri[16+g*4+1], iv);
            iv = fmaf(h0.z, Wri[16+g*4+2], iv); iv = fmaf(h0.w, Wri[16+g*4+3], iv);
            jv = fmaf(h.x,  Wrj[g*4+0], jv);  jv = fmaf(h.y,  Wrj[g*4+1], jv);
            jv = fmaf(h.z,  Wrj[g*4+2], jv);  jv = fmaf(h.w,  Wrj[g*4+3], jv);
        }
        val = iv * jv;
    }
#pragma unroll
    for (int off = 32; off > 0; off >>= 1)
        val += __shfl_xor(val, off, 64);
    __shared__ float wsum[4];
    int w = threadIdx.x >> 6;
    if ((threadIdx.x & 63) == 0) wsum[w] = val;
    __syncthreads();
    if (threadIdx.x == 0)
        atomicAdd(out, wsum[0] + wsum[1] + wsum[2] + wsum[3]);
}

// ---------------- launch ----------------
extern "C" void kernel_launch(void* const* d_in, const int* in_sizes, int n_in,
                              void* d_out, int out_size, void* d_ws, size_t ws_size,
                              hipStream_t stream)
{
    const float* node_features = (const float*)d_in[0];
    const float* edge_features = (const float*)d_in[1];
    const float* W_init = (const float*)d_in[2];
    const float* b_init = (const float*)d_in[3];
    const float* W_edge = (const float*)d_in[4];
    const float* b_edge = (const float*)d_in[5];
    const float* Wi_gru = (const float*)d_in[6];
    const float* Wh_gru = (const float*)d_in[7];
    const float* bi_gru = (const float*)d_in[8];
    const float* bh_gru = (const float*)d_in[9];
    const float* W_ri = (const float*)d_in[10];
    const float* b_ri = (const float*)d_in[11];
    const float* W_rj = (const float*)d_in[12];
    const float* b_rj = (const float*)d_in[13];
    const int* receivers = (const int*)d_in[14];
    const int* senders   = (const int*)d_in[15];
    float* out = (float*)d_out;

    // workspace carve: ~34 MB
    float* fb      = (float*)d_ws;
    float* hidden0 = fb;                 // 400000
    float* hidA    = fb + 400000;        // 400000
    float* hidB    = fb + 800000;        // 400000
    float* emsg    = fb + 1200000;       // 6400000 (E*16)
    int* ib    = (int*)(fb + 7600000);
    int* cnt_s = ib;                     // 25024
    int* cnt_r = ib + 25024;             // 25024
    int* srow  = ib + 50048;             // 25024
    int* rrow  = ib + 75072;             // 25024
    int* scur  = ib + 100096;            // 25024
    int* rcur  = ib + 125120;            // 25024
    int* eids  = ib + 150144;            // 400000
    int* dpos  = ib + 550144;            // 400000

    dim3 b256(256);
    int grid_n16 = (N_NODES * 16 + 255) / 256;   // 1563
    int grid_e   = (N_EDGES + 255) / 256;        // 1563
    int grid_n   = (N_NODES + 255) / 256;        // 98

    k_init<<<grid_n16, b256, 0, stream>>>(node_features, W_init, b_init,
                                          hidden0, hidA, cnt_s, cnt_r);
    k_hist<<<grid_e, b256, 0, stream>>>(senders, receivers, cnt_s, cnt_r);
    k_scan<<<2, 1024, 0, stream>>>(cnt_s, cnt_r, srow, scur, rrow, rcur, out);
    k_scatter<<<grid_e, b256, 0, stream>>>(senders, receivers, scur, rcur, eids, dpos);

    float* hin = hidA;
    float* hout = hidB;
    for (int it = 0; it < 3; ++it) {
        k_msg<<<grid_n16, b256, 0, stream>>>(hin, edge_features, W_edge, b_edge,
                                             srow, eids, dpos, emsg);
        k_gru<<<grid_n16, b256, 0, stream>>>(hin, emsg, rrow, Wi_gru, Wh_gru,
                                             bi_gru, bh_gru, hout);
        float* t = hin; hin = hout; hout = t;
    }

    k_readout<<<grid_n, b256, 0, stream>>>(hin, hidden0, W_ri, b_ri, W_rj, b_rj, out);
}

// Round 4
// 510.157 us; speedup vs baseline: 1.0543x; 1.0543x over previous
//
#include <hip/hip_runtime.h>

#define N_NODES 25000
#define N_EDGES 400000

// ---------------- fast transcendentals (fp32, ~2ulp) ----------------
__device__ __forceinline__ float fast_sigmoid(float x) {
    return __builtin_amdgcn_rcpf(1.0f + __expf(-x));
}
__device__ __forceinline__ float fast_tanh(float x) {
    return 1.0f - 2.0f * __builtin_amdgcn_rcpf(__expf(2.0f * x) + 1.0f);
}

// XOR swizzle: lane j gets value from lane j^k (stays in 16-lane group, k<16)
#define SWZF(x, k) __int_as_float(__builtin_amdgcn_ds_swizzle(__float_as_int(x), ((k) << 10) | 0x1F))
// Broadcast lane l (0..15) of the 16-lane group to all 16: src=(lane&0x10)|l
#define BC16(x, l) __int_as_float(__builtin_amdgcn_ds_swizzle(__float_as_int(x), ((l) << 5) | 0x10))

// ---------------- K1: hidden0 = nf @ W_init + b_init ; copy; zero cnts --------
__global__ void __launch_bounds__(256) k_init(
        const float* __restrict__ nf, const float* __restrict__ Wini,
        const float* __restrict__ bini,
        float* __restrict__ hidden0, float* __restrict__ hid,
        int* __restrict__ cnt_s, int* __restrict__ cnt_r)
{
    int gtid = blockIdx.x * 256 + threadIdx.x;
    if (gtid <= N_NODES) { cnt_s[gtid] = 0; cnt_r[gtid] = 0; }
    int node = gtid >> 4;
    int j = gtid & 15;
    if (node >= N_NODES) return;

    const float4* nf4 = (const float4*)(nf + node * 32);
    float acc = bini[j];
#pragma unroll
    for (int g = 0; g < 8; ++g) {
        float4 v = nf4[g];
        acc = fmaf(v.x, Wini[(g*4+0)*16 + j], acc);
        acc = fmaf(v.y, Wini[(g*4+1)*16 + j], acc);
        acc = fmaf(v.z, Wini[(g*4+2)*16 + j], acc);
        acc = fmaf(v.w, Wini[(g*4+3)*16 + j], acc);
    }
    hidden0[node*16 + j] = acc;
    hid[node*16 + j] = acc;
}

// ---------------- CSR build ----------------
__global__ void __launch_bounds__(256) k_hist(const int* __restrict__ send,
        const int* __restrict__ recv,
        int* __restrict__ cnt_s, int* __restrict__ cnt_r)
{
    int e = blockIdx.x * 256 + threadIdx.x;
    if (e < N_EDGES) {
        atomicAdd(&cnt_s[send[e]], 1);
        atomicAdd(&cnt_r[recv[e]], 1);
    }
}

// grid=2: block 0 scans sender counts, block 1 scans receiver counts
__global__ void __launch_bounds__(1024) k_scan(
        const int* __restrict__ cnt_s, const int* __restrict__ cnt_r,
        int* __restrict__ srow, int* __restrict__ scur,
        int* __restrict__ rrow, int* __restrict__ rcur,
        float* __restrict__ out)
{
    const int* cnt = (blockIdx.x == 0) ? cnt_s : cnt_r;
    int* row = (blockIdx.x == 0) ? srow : rrow;
    int* cur = (blockIdx.x == 0) ? scur : rcur;

    __shared__ int sums[1024];
    int t = threadIdx.x;
    const int CH = (N_NODES + 1023) / 1024 + 1;   // 25 -> covers 25600
    int base = t * CH;
    int s = 0;
    for (int i = 0; i < CH; ++i) {
        int idx = base + i;
        if (idx < N_NODES) s += cnt[idx];
    }
    sums[t] = s;
    __syncthreads();
    for (int off = 1; off < 1024; off <<= 1) {
        int add = (t >= off) ? sums[t - off] : 0;
        __syncthreads();
        sums[t] += add;
        __syncthreads();
    }
    int run = sums[t] - s;
    for (int i = 0; i < CH; ++i) {
        int idx = base + i;
        if (idx < N_NODES) {
            row[idx] = run;
            cur[idx] = run;
            run += cnt[idx];
        }
    }
    if (t == 0) {
        row[N_NODES] = N_EDGES;
        if (blockIdx.x == 0) out[0] = 0.0f;
    }
}

// eids[sp]=e ; gpos[rp]=sp ; optionally efp[sp,:]=ef[e,:]
__global__ void __launch_bounds__(256) k_scatter(const int* __restrict__ send,
        const int* __restrict__ recv,
        int* __restrict__ scur, int* __restrict__ rcur,
        int* __restrict__ eids, int* __restrict__ gpos,
        const float* __restrict__ ef, float* __restrict__ efp)
{
    int e = blockIdx.x * 256 + threadIdx.x;
    if (e < N_EDGES) {
        int s = send[e];
        int r = recv[e];
        int sp = atomicAdd(&scur[s], 1);
        int rp = atomicAdd(&rcur[r], 1);
        eids[sp] = e;
        gpos[rp] = sp;
        if (efp) {
            const float4* src = (const float4*)(ef + (size_t)e * 16);
            float4* dst = (float4*)(efp + (size_t)sp * 16);
            dst[0] = src[0]; dst[1] = src[1]; dst[2] = src[2]; dst[3] = src[3];
        }
    }
}

// ---------------- per-sender q computation helper ----------------
__device__ __forceinline__ void load_q(const float* __restrict__ hid, int s, int m,
        const float* __restrict__ We, const float* __restrict__ be,
        float* __restrict__ q, float& qb)
{
    float h[16];
    {
        const float4* h4 = (const float4*)(hid + s*16);
        float4 a = h4[0], b = h4[1], c = h4[2], d = h4[3];
        h[0]=a.x;  h[1]=a.y;  h[2]=a.z;  h[3]=a.w;
        h[4]=b.x;  h[5]=b.y;  h[6]=b.z;  h[7]=b.w;
        h[8]=c.x;  h[9]=c.y;  h[10]=c.z; h[11]=c.w;
        h[12]=d.x; h[13]=d.y; h[14]=d.z; h[15]=d.w;
    }
#pragma unroll
    for (int f = 0; f < 16; ++f) {
        const float4* wf = (const float4*)(We + f*256 + m*16);
        float4 a = wf[0], b = wf[1], c = wf[2], d = wf[3];
        float acc;
        acc  = a.x*h[0]  + a.y*h[1]  + a.z*h[2]  + a.w*h[3];
        acc += b.x*h[4]  + b.y*h[5]  + b.z*h[6]  + b.w*h[7];
        acc += c.x*h[8]  + c.y*h[9]  + c.z*h[10] + c.w*h[11];
        acc += d.x*h[12] + d.y*h[13] + d.z*h[14] + d.w*h[15];
        q[f] = acc;
    }
    {
        const float4* bf = (const float4*)(be + m*16);
        float4 a = bf[0], b = bf[1], c = bf[2], d = bf[3];
        qb  = a.x*h[0]  + a.y*h[1]  + a.z*h[2]  + a.w*h[3];
        qb += b.x*h[4]  + b.y*h[5]  + b.z*h[6]  + b.w*h[7];
        qb += c.x*h[8]  + c.y*h[9]  + c.z*h[10] + c.w*h[11];
        qb += d.x*h[12] + d.y*h[13] + d.z*h[14] + d.w*h[15];
    }
}

__device__ __forceinline__ float edge_dot(float4 e0, float4 e1, float4 e2, float4 e3,
        const float* __restrict__ q, float qb)
{
    float a = qb;
    a = fmaf(e0.x, q[0],  a);
    a = fmaf(e0.y, q[1],  a);
    a = fmaf(e0.z, q[2],  a);
    a = fmaf(e0.w, q[3],  a);
    a = fmaf(e1.x, q[4],  a);
    a = fmaf(e1.y, q[5],  a);
    a = fmaf(e1.z, q[6],  a);
    a = fmaf(e1.w, q[7],  a);
    a = fmaf(e2.x, q[8],  a);
    a = fmaf(e2.y, q[9],  a);
    a = fmaf(e2.z, q[10], a);
    a = fmaf(e2.w, q[11], a);
    a = fmaf(e3.x, q[12], a);
    a = fmaf(e3.y, q[13], a);
    a = fmaf(e3.z, q[14], a);
    a = fmaf(e3.w, q[15], a);
    return a;
}

// ---------------- K3a: fully-sequential message kernel (needs efp) ----------
// group = sender s; lane = message dim m. Reads efp[i] and writes emsg[i]
// sequentially over the sender's slot range — zero scattered traffic.
__global__ void __launch_bounds__(256) k_msg_seq(
        const float* __restrict__ hid, const float* __restrict__ efp,
        const float* __restrict__ We, const float* __restrict__ be,
        const int* __restrict__ srow, float* __restrict__ emsg)
{
    int gtid = blockIdx.x * 256 + threadIdx.x;
    int s = gtid >> 4;
    int m = gtid & 15;
    if (s >= N_NODES) return;

    float q[16], qb;
    load_q(hid, s, m, We, be, q, qb);

    int beg = srow[s];
    int end = srow[s + 1];
    for (int i = beg; i < end; ++i) {
        const float4* e4 = (const float4*)(efp + (size_t)i*16);
        float4 e0 = e4[0], e1 = e4[1], e2 = e4[2], e3 = e4[3];
        emsg[(size_t)i*16 + m] = edge_dot(e0, e1, e2, e3, q, qb);
    }
}

// ---------------- K3b: fallback (no efp room): gather ef via eids ----------
__global__ void __launch_bounds__(256) k_msg_gather(
        const float* __restrict__ hid, const float* __restrict__ ef,
        const float* __restrict__ We, const float* __restrict__ be,
        const int* __restrict__ srow, const int* __restrict__ eids,
        float* __restrict__ emsg)
{
    int gtid = blockIdx.x * 256 + threadIdx.x;
    int s = gtid >> 4;
    int m = gtid & 15;
    if (s >= N_NODES) return;

    float q[16], qb;
    load_q(hid, s, m, We, be, q, qb);

    int beg = srow[s];
    int end = srow[s + 1];
    for (int i = beg; i < end; ++i) {
        int e = eids[i];
        const float4* e4 = (const float4*)(ef + (size_t)e*16);
        float4 e0 = e4[0], e1 = e4[1], e2 = e4[2], e3 = e4[3];
        emsg[(size_t)i*16 + m] = edge_dot(e0, e1, e2, e3, q, qb);
    }
}

// ---------------- K4: gather segment-sum + GRU (T=32), in-place ----------
// group = node n, lane j. msum_j = sum over receiver-CSR positions p of
// emsg[gpos[p]*16+j] (random 64B reads, 4-way unrolled, latency-hidable).
__global__ void __launch_bounds__(256) k_gru(
        float* __restrict__ hid, const float* __restrict__ emsg,
        const int* __restrict__ rrow, const int* __restrict__ gpos,
        const float* __restrict__ Wi, const float* __restrict__ Wh,
        const float* __restrict__ bi, const float* __restrict__ bh)
{
    int gtid = blockIdx.x * 256 + threadIdx.x;
    int node = gtid >> 4;
    int j = gtid & 15;
    if (node >= N_NODES) return;

    float Wz[16], Wr[16], Wc[16];
#pragma unroll
    for (int k = 0; k < 16; ++k) {
        int l = j ^ k;
        Wz[k] = Wh[l*48 + j];
        Wr[k] = Wh[l*48 + 16 + j];
        Wc[k] = Wh[l*48 + 32 + j];
    }
    float Wiz = Wi[j], Wir = Wi[16+j], Wih = Wi[32+j];
    float cz   = bi[j] + bh[j];
    float cr   = bi[16+j] + bh[16+j];
    float bih_ = bi[32+j];
    float bhh_ = bh[32+j];

    // segment sum via gather (4 independent loads in flight)
    float msum = 0.0f;
    {
        int beg = rrow[node];
        int end = rrow[node + 1];
        int p = beg;
        for (; p + 3 < end; p += 4) {
            int s0 = gpos[p], s1 = gpos[p+1], s2 = gpos[p+2], s3 = gpos[p+3];
            float v0 = emsg[(size_t)s0*16 + j];
            float v1 = emsg[(size_t)s1*16 + j];
            float v2 = emsg[(size_t)s2*16 + j];
            float v3 = emsg[(size_t)s3*16 + j];
            msum += (v0 + v1) + (v2 + v3);
        }
        for (; p < end; ++p)
            msum += emsg[(size_t)gpos[p]*16 + j];
    }

    float x[16];
    {
        const float4* a4 = (const float4*)(hid + node * 16);
#pragma unroll
        for (int g = 0; g < 4; ++g) {
            float4 v = a4[g];
            x[g*4+0]=v.x; x[g*4+1]=v.y; x[g*4+2]=v.z; x[g*4+3]=v.w;
        }
    }

    float hn = 0.0f;

#define STEPK(k) { float v = SWZF(hn, k); \
        az = fmaf(v, Wz[k], az); ar = fmaf(v, Wr[k], ar); ac = fmaf(v, Wc[k], ac); }

#define GRU_STEP(XV) { float xv = (XV); \
        float az = fmaf(xv, Wiz, cz); \
        float ar = fmaf(xv, Wir, cr); \
        float ac = bhh_; \
        az = fmaf(hn, Wz[0], az); \
        ar = fmaf(hn, Wr[0], ar); \
        ac = fmaf(hn, Wc[0], ac); \
        STEPK(1)  STEPK(2)  STEPK(3)  STEPK(4)  STEPK(5) \
        STEPK(6)  STEPK(7)  STEPK(8)  STEPK(9)  STEPK(10) \
        STEPK(11) STEPK(12) STEPK(13) STEPK(14) STEPK(15) \
        float zg  = fast_sigmoid(az); \
        float rg  = fast_sigmoid(ar); \
        float hc = fast_tanh(fmaf(xv, Wih, bih_) + rg * ac); \
        hn = fmaf(zg, hn - hc, hc); }

    GRU_STEP(x[0])  GRU_STEP(x[1])  GRU_STEP(x[2])  GRU_STEP(x[3])
    GRU_STEP(x[4])  GRU_STEP(x[5])  GRU_STEP(x[6])  GRU_STEP(x[7])
    GRU_STEP(x[8])  GRU_STEP(x[9])  GRU_STEP(x[10]) GRU_STEP(x[11])
    GRU_STEP(x[12]) GRU_STEP(x[13]) GRU_STEP(x[14]) GRU_STEP(x[15])

    GRU_STEP(BC16(msum, 0))  GRU_STEP(BC16(msum, 1))
    GRU_STEP(BC16(msum, 2))  GRU_STEP(BC16(msum, 3))
    GRU_STEP(BC16(msum, 4))  GRU_STEP(BC16(msum, 5))
    GRU_STEP(BC16(msum, 6))  GRU_STEP(BC16(msum, 7))
    GRU_STEP(BC16(msum, 8))  GRU_STEP(BC16(msum, 9))
    GRU_STEP(BC16(msum, 10)) GRU_STEP(BC16(msum, 11))
    GRU_STEP(BC16(msum, 12)) GRU_STEP(BC16(msum, 13))
    GRU_STEP(BC16(msum, 14)) GRU_STEP(BC16(msum, 15))

#undef GRU_STEP
#undef STEPK

    hid[node*16 + j] = hn;   // in-place safe: pointwise per node
}

// ---------------- K5: readout ----------------
__global__ void __launch_bounds__(256) k_readout(
        const float* __restrict__ hid, const float* __restrict__ hid0,
        const float* __restrict__ Wri, const float* __restrict__ bri,
        const float* __restrict__ Wrj, const float* __restrict__ brj,
        float* __restrict__ out)
{
    int n = blockIdx.x * 256 + threadIdx.x;
    float val = 0.0f;
    if (n < N_NODES) {
        const float4* h4 = (const float4*)(hid + n * 16);
        const float4* g4 = (const float4*)(hid0 + n * 16);
        float iv = bri[0];
        float jv = brj[0];
#pragma unroll
        for (int g = 0; g < 4; ++g) {
            float4 h  = h4[g];
            float4 h0 = g4[g];
            iv = fmaf(h.x,  Wri[g*4+0], iv);  iv = fmaf(h.y,  Wri[g*4+1], iv);
            iv = fmaf(h.z,  Wri[g*4+2], iv);  iv = fmaf(h.w,  Wri[g*4+3], iv);
            iv = fmaf(h0.x, Wri[16+g*4+0], iv); iv = fmaf(h0.y, Wri[16+g*4+1], iv);
            iv = fmaf(h0.z, Wri[16+g*4+2], iv); iv = fmaf(h0.w, Wri[16+g*4+3], iv);
            jv = fmaf(h.x,  Wrj[g*4+0], jv);  jv = fmaf(h.y,  Wrj[g*4+1], jv);
            jv = fmaf(h.z,  Wrj[g*4+2], jv);  jv = fmaf(h.w,  Wrj[g*4+3], jv);
        }
        val = iv * jv;
    }
#pragma unroll
    for (int off = 32; off > 0; off >>= 1)
        val += __shfl_xor(val, off, 64);
    __shared__ float wsum[4];
    int w = threadIdx.x >> 6;
    if ((threadIdx.x & 63) == 0) wsum[w] = val;
    __syncthreads();
    if (threadIdx.x == 0)
        atomicAdd(out, wsum[0] + wsum[1] + wsum[2] + wsum[3]);
}

// ---------------- launch ----------------
extern "C" void kernel_launch(void* const* d_in, const int* in_sizes, int n_in,
                              void* d_out, int out_size, void* d_ws, size_t ws_size,
                              hipStream_t stream)
{
    const float* node_features = (const float*)d_in[0];
    const float* edge_features = (const float*)d_in[1];
    const float* W_init = (const float*)d_in[2];
    const float* b_init = (const float*)d_in[3];
    const float* W_edge = (const float*)d_in[4];
    const float* b_edge = (const float*)d_in[5];
    const float* Wi_gru = (const float*)d_in[6];
    const float* Wh_gru = (const float*)d_in[7];
    const float* bi_gru = (const float*)d_in[8];
    const float* bh_gru = (const float*)d_in[9];
    const float* W_ri = (const float*)d_in[10];
    const float* b_ri = (const float*)d_in[11];
    const float* W_rj = (const float*)d_in[12];
    const float* b_rj = (const float*)d_in[13];
    const int* receivers = (const int*)d_in[14];
    const int* senders   = (const int*)d_in[15];
    float* out = (float*)d_out;

    // workspace carve
    float* fb      = (float*)d_ws;
    float* hidden0 = fb;                    // 400000
    float* hidA    = fb + 400000;           // 400000 (in-place GRU)
    float* emsg    = fb + 800000;           // 6400000 (E*16)
    int* ib    = (int*)(fb + 7200000);
    int* cnt_s = ib;                        // 25024
    int* cnt_r = ib + 25024;                // 25024
    int* srow  = ib + 50048;                // 25024
    int* rrow  = ib + 75072;                // 25024
    int* scur  = ib + 100096;               // 25024
    int* rcur  = ib + 125120;               // 25024
    int* eids  = ib + 150144;               // 400000
    int* gpos  = ib + 550144;               // 400000 -> ints end @ 950144
    float* efp = fb + 8150144;              // optional 6400000 (E*16)
    const size_t NEED_EFP = (size_t)(8150144 + 6400000) * 4;  // 58.2 MB
    bool use_efp = ws_size >= NEED_EFP;     // constant per-process: graph-safe

    dim3 b256(256);
    int grid_n16 = (N_NODES * 16 + 255) / 256;   // 1563
    int grid_e   = (N_EDGES + 255) / 256;        // 1563
    int grid_n   = (N_NODES + 255) / 256;        // 98

    k_init<<<grid_n16, b256, 0, stream>>>(node_features, W_init, b_init,
                                          hidden0, hidA, cnt_s, cnt_r);
    k_hist<<<grid_e, b256, 0, stream>>>(senders, receivers, cnt_s, cnt_r);
    k_scan<<<2, 1024, 0, stream>>>(cnt_s, cnt_r, srow, scur, rrow, rcur, out);
    k_scatter<<<grid_e, b256, 0, stream>>>(senders, receivers, scur, rcur,
                                           eids, gpos, edge_features,
                                           use_efp ? efp : (float*)nullptr);

    for (int it = 0; it < 3; ++it) {
        if (use_efp)
            k_msg_seq<<<grid_n16, b256, 0, stream>>>(hidA, efp, W_edge, b_edge,
                                                     srow, emsg);
        else
            k_msg_gather<<<grid_n16, b256, 0, stream>>>(hidA, edge_features,
                                                        W_edge, b_edge, srow,
                                                        eids, emsg);
        k_gru<<<grid_n16, b256, 0, stream>>>(hidA, emsg, rrow, gpos,
                                             Wi_gru, Wh_gru, bi_gru, bh_gru);
    }

    k_readout<<<grid_n, b256, 0, stream>>>(hidA, hidden0, W_ri, b_ri, W_rj, b_rj, out);
}